// Round 2
// baseline (18656.650 us; speedup 1.0000x reference)
//
#include <hip/hip_runtime.h>
#include <hip/hip_fp16.h>

#define HID   1024
#define NBAT  64
#define NBLK  256
#define NTHR  256
#define AROW  2056              // 2048 + 8 pad (f16 elems)
#define AVEC  257               // AROW/8

typedef _Float16 f16;
typedef __attribute__((ext_vector_type(8))) _Float16 f16x8;
typedef __attribute__((ext_vector_type(4))) float f32x4;

// LDS layout (bytes)
#define A_BYTES   (2 * 16 * AROW * 2)    // 131584: weights, 2 layers x 16 rows x 2056 f16
#define SCR_OFF   A_BYTES                // f32 [4 kg][16 rows][64 batch] = 16384
#define C_OFF     (SCR_OFF + 16384)      // f32 [2 layers][4 units][64 batch] = 2048
#define BIAS_OFF  (C_OFF + 2048)         // f32 [2][16] = 128
#define LDS_BYTES (BIAS_OFF + 128)       // 150144 < 160 KiB

__device__ __forceinline__ float sigm(float x) { return 1.f / (1.f + __expf(-x)); }
__device__ __forceinline__ float tanh_f(float x) {
  float xc = fminf(fmaxf(x, -10.f), 10.f);
  float e = __expf(2.f * xc);
  return (e - 1.f) / (e + 1.f);
}

// Monotone-epoch grid barrier. bar[0]=arrival count (never reset), bar[1]=epoch.
// All threads fence on both sides: release side writes XCD-L2 back (h stores),
// acquire side invalidates L1/L2 (h addresses recur every 4 phases -> would be
// stale in the 4MiB per-XCD L2 otherwise).
__device__ __forceinline__ void grid_barrier(int* bar, int epoch) {
  __threadfence();
  __syncthreads();
  if (threadIdx.x == 0) {
    int prev = __hip_atomic_fetch_add(&bar[0], 1, __ATOMIC_ACQ_REL, __HIP_MEMORY_SCOPE_AGENT);
    if (prev == epoch * NBLK - 1) {
      __hip_atomic_store(&bar[1], epoch, __ATOMIC_RELEASE, __HIP_MEMORY_SCOPE_AGENT);
    } else {
      while (__hip_atomic_load(&bar[1], __ATOMIC_ACQUIRE, __HIP_MEMORY_SCOPE_AGENT) < epoch)
        __builtin_amdgcn_s_sleep(2);
    }
  }
  __syncthreads();
  __threadfence();
}

__global__ void bar_init(int* bar) { bar[0] = 0; bar[1] = 0; }

// Block b owns hidden units [4b,4b+4) for both layers.
// LDS weight tile row m = g*4 + j (gate g in {i,f,g,o}, unit j in 0..3),
// fused K: [W_ih row (1024) | W_hh row (1024)], stored f16.
// hbuf: f16 [layer][parity][64][1024], double-buffered by step parity.
__global__ __launch_bounds__(NTHR, 1) void lstm_kernel(
    const float* __restrict__ x0, const float* __restrict__ h0,
    const float* __restrict__ c0, const float* __restrict__ Wih,
    const float* __restrict__ Whh, const float* __restrict__ bih,
    const float* __restrict__ bhh, const int* __restrict__ lenp,
    float* __restrict__ out, int* __restrict__ bar,
    f16* __restrict__ hbuf, f16* __restrict__ xf16)
{
  extern __shared__ char smem[];
  f16*   Alds  = (f16*)smem;
  float* scr   = (float*)(smem + SCR_OFF);
  float* cS    = (float*)(smem + C_OFF);
  float* biasS = (float*)(smem + BIAS_OFF);

  const int tid  = threadIdx.x;
  const int blk  = blockIdx.x;
  const int wave = tid >> 6;
  const int lane = tid & 63;
  const int quad = lane >> 4;
  const int l15  = lane & 15;
  const int T    = *lenp;

  // ---- stage weights (f32 -> f16) into LDS: 64 rows-of-1024, 4 threads/row ----
  {
    int r    = tid >> 2;            // 0..63
    int part = tid & 3;             // 256-elem chunk within the 1024-row
    int l    = r >> 5;
    int m    = (r >> 1) & 15;
    int half = r & 1;               // 0: W_ih, 1: W_hh
    int g    = m >> 2, j = m & 3;
    size_t grow = (size_t)g * HID + blk * 4 + j;
    const float* srcW = (half ? Whh : Wih) + ((size_t)l * 4 * HID + grow) * HID + part * 256;
    f16x8* dst = (f16x8*)(Alds + (size_t)(l * 16 + m) * AROW + half * HID + part * 256);
    const float4* s4 = (const float4*)srcW;
    #pragma unroll 4
    for (int i = 0; i < 32; ++i) {
      float4 w0 = s4[2 * i], w1 = s4[2 * i + 1];
      f16x8 o = {(f16)w0.x, (f16)w0.y, (f16)w0.z, (f16)w0.w,
                 (f16)w1.x, (f16)w1.y, (f16)w1.z, (f16)w1.w};
      dst[i] = o;
    }
  }
  // ---- biases (b_ih + b_hh, fp32) ----
  if (tid < 32) {
    int l = tid >> 4, m = tid & 15;
    int g = m >> 2, j = m & 3;
    size_t row = (size_t)g * HID + blk * 4 + j;
    biasS[l * 16 + m] = bih[(size_t)l * 4 * HID + row] + bhh[(size_t)l * 4 * HID + row];
  }
  // ---- c state (fp32, CU-local forever) + h0 -> hbuf parity 1 + x0 -> f16 ----
  {
    int j = tid >> 6, n = tid & 63;
    #pragma unroll
    for (int l = 0; l < 2; ++l) {
      cS[l * 256 + j * 64 + n] =
          c0[(size_t)l * NBAT * HID + (size_t)n * HID + blk * 4 + j];
      hbuf[(size_t)(l * 2 + 1) * NBAT * HID + (size_t)n * HID + blk * 4 + j] =
          (f16)h0[(size_t)l * NBAT * HID + (size_t)n * HID + blk * 4 + j];
    }
    size_t e = (size_t)blk * 256 + tid;   // 256 blocks x 256 elems = 65536 = all of x0
    xf16[e] = (f16)x0[e];
  }

  int epoch = 1;
  grid_barrier(bar, epoch++);

  const f16x8* Av = (const f16x8*)Alds;

  for (int t = 0; t < T; ++t) {
    const int wp = t & 1, rp = wp ^ 1;
    #pragma unroll 1
    for (int l = 0; l < 2; ++l) {
      // ---- B source for this wave's K-quarter ----
      const f16* src; int col0;
      const int kbase = wave * 512;
      if (l == 0) {
        if (kbase < 1024) { src = (t == 0) ? xf16 : hbuf + (size_t)(2 + rp) * NBAT * HID; col0 = kbase; }
        else              { src = hbuf + (size_t)(0 + rp) * NBAT * HID; col0 = kbase - 1024; }
      } else {
        if (kbase < 1024) { src = hbuf + (size_t)(0 + wp) * NBAT * HID; col0 = kbase; }
        else              { src = hbuf + (size_t)(2 + rp) * NBAT * HID; col0 = kbase - 1024; }
      }
      const f16* r0 = src + (size_t)(l15 +  0) * HID + col0 + quad * 8;
      const f16* r1 = src + (size_t)(l15 + 16) * HID + col0 + quad * 8;
      const f16* r2 = src + (size_t)(l15 + 32) * HID + col0 + quad * 8;
      const f16* r3 = src + (size_t)(l15 + 48) * HID + col0 + quad * 8;

      // ---- MFMA: 16 gate-rows x 64 batch over this wave's K=512 ----
      int aoff = (l * 16 + l15) * AVEC + wave * 64 + quad;
      f32x4 a0 = {0.f, 0.f, 0.f, 0.f}, a1 = a0, a2 = a0, a3 = a0;
      #pragma unroll
      for (int kk = 0; kk < 16; ++kk) {
        f16x8 af  = Av[aoff + kk * 4];
        f16x8 b0v = *(const f16x8*)(r0 + kk * 32);
        f16x8 b1v = *(const f16x8*)(r1 + kk * 32);
        f16x8 b2v = *(const f16x8*)(r2 + kk * 32);
        f16x8 b3v = *(const f16x8*)(r3 + kk * 32);
        a0 = __builtin_amdgcn_mfma_f32_16x16x32_f16(af, b0v, a0, 0, 0, 0);
        a1 = __builtin_amdgcn_mfma_f32_16x16x32_f16(af, b1v, a1, 0, 0, 0);
        a2 = __builtin_amdgcn_mfma_f32_16x16x32_f16(af, b2v, a2, 0, 0, 0);
        a3 = __builtin_amdgcn_mfma_f32_16x16x32_f16(af, b3v, a3, 0, 0, 0);
      }
      // ---- partials to LDS scratch (C/D: col=lane&15, row=quad*4+reg) ----
      float* sc = scr + wave * 1024;
      #pragma unroll
      for (int r = 0; r < 4; ++r) {
        int base = (quad * 4 + r) * 64 + l15;
        sc[base +  0] = a0[r];
        sc[base + 16] = a1[r];
        sc[base + 32] = a2[r];
        sc[base + 48] = a3[r];
      }
      __syncthreads();

      // ---- elementwise: thread = (unit j, batch n); all gates CU-local ----
      {
        int j = tid >> 6, n = tid & 63;
        float gate[4];
        #pragma unroll
        for (int g = 0; g < 4; ++g) {
          int b0i = (g * 4 + j) * 64 + n;
          gate[g] = scr[b0i] + scr[1024 + b0i] + scr[2048 + b0i] + scr[3072 + b0i]
                  + biasS[l * 16 + g * 4 + j];
        }
        float cold = cS[l * 256 + j * 64 + n];
        float cn = sigm(gate[1]) * cold + sigm(gate[0]) * tanh_f(gate[2]);
        float hn = sigm(gate[3]) * tanh_f(cn);
        cS[l * 256 + j * 64 + n] = cn;
        hbuf[(size_t)(l * 2 + wp) * NBAT * HID + (size_t)n * HID + blk * 4 + j] = (f16)hn;
        if (l == 1)
          out[(size_t)n * T * HID + (size_t)t * HID + blk * 4 + j] = hn;
      }
      grid_barrier(bar, epoch++);
    }
  }
}

extern "C" void kernel_launch(void* const* d_in, const int* in_sizes, int n_in,
                              void* d_out, int out_size, void* d_ws, size_t ws_size,
                              hipStream_t stream) {
  const float* x0  = (const float*)d_in[0];
  const float* h0  = (const float*)d_in[1];
  const float* c0  = (const float*)d_in[2];
  const float* Wih = (const float*)d_in[3];
  const float* Whh = (const float*)d_in[4];
  const float* bih = (const float*)d_in[5];
  const float* bhh = (const float*)d_in[6];
  const int* lenp  = (const int*)d_in[7];
  float* out = (float*)d_out;

  int* bar  = (int*)d_ws;
  f16* hbuf = (f16*)((char*)d_ws + 256);          // 4 x 64 x 1024 f16 = 512 KB
  f16* xbuf = hbuf + (size_t)4 * NBAT * HID;      // 64 x 1024 f16 = 128 KB

  hipFuncSetAttribute((const void*)lstm_kernel,
                      hipFuncAttributeMaxDynamicSharedMemorySize, LDS_BYTES);

  bar_init<<<1, 1, 0, stream>>>(bar);

  void* args[] = {&x0, &h0, &c0, &Wih, &Whh, &bih, &bhh, &lenp, &out, &bar, &hbuf, &xbuf};
  hipLaunchCooperativeKernel((void*)lstm_kernel, dim3(NBLK), dim3(NTHR),
                             args, LDS_BYTES, stream);
}

// Round 3
// 5607.166 us; speedup vs baseline: 3.3273x; 3.3273x over previous
//
#include <hip/hip_runtime.h>
#include <hip/hip_fp16.h>

#define HID   1024
#define NBAT  64
#define NBLK  256
#define NTHR  256
#define AROW  2056              // 2048 + 8 pad (f16 elems)
#define AVEC  257               // AROW/8

typedef _Float16 f16;
typedef unsigned long long u64;
typedef __attribute__((ext_vector_type(8))) _Float16 f16x8;
typedef __attribute__((ext_vector_type(4))) float f32x4;

// LDS layout (bytes)
#define A_BYTES   (2 * 16 * AROW * 2)    // 131584: weights, 2 layers x 16 rows x 2056 f16
#define SCR_OFF   A_BYTES                // f32 [4 kg][16 rows][64 batch] = 16384
#define C_OFF     (SCR_OFF + 16384)      // f32 [2 layers][4 units][64 batch] = 2048
#define BIAS_OFF  (C_OFF + 2048)         // f32 [2][16] = 128
#define HS_OFF    (BIAS_OFF + 128)       // f16 [64 batch][4 units] = 512
#define LDS_BYTES (HS_OFF + 512)         // 150656 < 160 KiB

__device__ __forceinline__ float sigm(float x) { return 1.f / (1.f + __expf(-x)); }
__device__ __forceinline__ float tanh_f(float x) {
  float xc = fminf(fmaxf(x, -10.f), 10.f);
  float e = __expf(2.f * xc);
  return (e - 1.f) / (e + 1.f);
}

// Coherent (device-scope, sc1) access helpers: write-through to MALL / read from
// MALL. Relaxed => NO buffer_inv / buffer_wbl2 cache-maintenance ops emitted.
__device__ __forceinline__ void st64c(void* p, u64 v) {
  __hip_atomic_store((u64*)p, v, __ATOMIC_RELAXED, __HIP_MEMORY_SCOPE_AGENT);
}
__device__ __forceinline__ u64 ld64c(const void* p) {
  return __hip_atomic_load((const u64*)p, __ATOMIC_RELAXED, __HIP_MEMORY_SCOPE_AGENT);
}
__device__ __forceinline__ f16x8 ld16c(const f16* p) {
  union { u64 q[2]; f16x8 v; } u;
  u.q[0] = ld64c(p);
  u.q[1] = ld64c(p + 4);
  return u.v;
}

__global__ void bar_init(int* bar) { bar[0] = 0; bar[16] = 0; }

// Block b owns hidden units [4b,4b+4) for both layers.
// LDS weight row m = g*4 + j (gate g in {i,f,g,o}, unit j in 0..3),
// fused K: [W_ih row (1024) | W_hh row (1024)], stored f16.
// hbuf: f16 [layer][parity][64][1024], double-buffered by step parity.
// All hbuf/xf16 traffic uses sc1 (agent-scope relaxed atomics) => coherent via
// MALL, no fences needed; barrier is waitcnt + relaxed atomics only.
__global__ __launch_bounds__(NTHR, 1) void lstm_kernel(
    const float* __restrict__ x0, const float* __restrict__ h0,
    const float* __restrict__ c0, const float* __restrict__ Wih,
    const float* __restrict__ Whh, const float* __restrict__ bih,
    const float* __restrict__ bhh, const int* __restrict__ lenp,
    float* __restrict__ out, int* __restrict__ bar,
    f16* __restrict__ hbuf, f16* __restrict__ xf16)
{
  extern __shared__ char smem[];
  f16*   Alds  = (f16*)smem;
  float* scr   = (float*)(smem + SCR_OFF);
  float* cS    = (float*)(smem + C_OFF);
  float* biasS = (float*)(smem + BIAS_OFF);
  f16*   hS    = (f16*)(smem + HS_OFF);     // [n][j] transpose buffer

  const int tid  = threadIdx.x;
  const int blk  = blockIdx.x;
  const int wave = tid >> 6;
  const int lane = tid & 63;
  const int quad = lane >> 4;
  const int l15  = lane & 15;
  const int T    = *lenp;

  // ---- stage weights (f32 -> f16) into LDS: 64 rows-of-1024, 4 threads/row ----
  {
    int r    = tid >> 2;            // 0..63
    int part = tid & 3;             // 256-elem chunk within the 1024-row
    int l    = r >> 5;
    int m    = (r >> 1) & 15;
    int half = r & 1;               // 0: W_ih, 1: W_hh
    int g    = m >> 2, j = m & 3;
    size_t grow = (size_t)g * HID + blk * 4 + j;
    const float* srcW = (half ? Whh : Wih) + ((size_t)l * 4 * HID + grow) * HID + part * 256;
    f16x8* dst = (f16x8*)(Alds + (size_t)(l * 16 + m) * AROW + half * HID + part * 256);
    const float4* s4 = (const float4*)srcW;
    #pragma unroll 4
    for (int i = 0; i < 32; ++i) {
      float4 w0 = s4[2 * i], w1 = s4[2 * i + 1];
      f16x8 o = {(f16)w0.x, (f16)w0.y, (f16)w0.z, (f16)w0.w,
                 (f16)w1.x, (f16)w1.y, (f16)w1.z, (f16)w1.w};
      dst[i] = o;
    }
  }
  // ---- biases (b_ih + b_hh, fp32) ----
  if (tid < 32) {
    int l = tid >> 4, m = tid & 15;
    int g = m >> 2, j = m & 3;
    size_t row = (size_t)g * HID + blk * 4 + j;
    biasS[l * 16 + m] = bih[(size_t)l * 4 * HID + row] + bhh[(size_t)l * 4 * HID + row];
  }
  // ---- c state (fp32, CU-local forever) ----
  {
    int j = tid >> 6, n = tid & 63;
    #pragma unroll
    for (int l = 0; l < 2; ++l)
      cS[l * 256 + j * 64 + n] =
          c0[(size_t)l * NBAT * HID + (size_t)n * HID + blk * 4 + j];
  }
  // ---- h0 -> hbuf parity 1 (sc1, 8B coalesced) ----
  if (tid < 128) {
    int l = tid >> 6, n = tid & 63;
    const float* hp = h0 + (size_t)l * NBAT * HID + (size_t)n * HID + blk * 4;
    union { u64 q; f16 h[4]; } pk;
    pk.h[0] = (f16)hp[0]; pk.h[1] = (f16)hp[1]; pk.h[2] = (f16)hp[2]; pk.h[3] = (f16)hp[3];
    st64c(hbuf + (size_t)(l * 2 + 1) * NBAT * HID + (size_t)n * HID + blk * 4, pk.q);
  }
  // ---- x0 -> f16 (sc1): blocks 0..63 stage 1024 elems each ----
  if (blk < 64) {
    const float* xp = x0 + (size_t)blk * 1024 + tid * 4;
    union { u64 q; f16 h[4]; } pk;
    pk.h[0] = (f16)xp[0]; pk.h[1] = (f16)xp[1]; pk.h[2] = (f16)xp[2]; pk.h[3] = (f16)xp[3];
    st64c(xf16 + (size_t)blk * 1024 + tid * 4, pk.q);
  }

  // ---- grid barrier (no cache-maintenance ops) ----
  int epoch = 1;
  #define GRID_BARRIER()                                                          \
    do {                                                                          \
      asm volatile("s_waitcnt vmcnt(0)" ::: "memory");                            \
      __syncthreads();                                                            \
      if (tid == 0) {                                                             \
        int prev = __hip_atomic_fetch_add(&bar[0], 1, __ATOMIC_RELAXED,           \
                                          __HIP_MEMORY_SCOPE_AGENT);              \
        if (prev == epoch * NBLK - 1) {                                           \
          __hip_atomic_store(&bar[16], epoch, __ATOMIC_RELAXED,                   \
                             __HIP_MEMORY_SCOPE_AGENT);                           \
        } else {                                                                  \
          while (__hip_atomic_load(&bar[16], __ATOMIC_RELAXED,                    \
                                   __HIP_MEMORY_SCOPE_AGENT) < epoch)             \
            __builtin_amdgcn_s_sleep(4);                                          \
        }                                                                         \
      }                                                                           \
      epoch++;                                                                    \
      __syncthreads();                                                            \
    } while (0)

  GRID_BARRIER();

  const f16x8* Av = (const f16x8*)Alds;

  for (int t = 0; t < T; ++t) {
    const int wp = t & 1, rp = wp ^ 1;
    #pragma unroll 1
    for (int l = 0; l < 2; ++l) {
      // ---- B source for this wave's K-quarter ----
      const f16* src; int col0;
      const int kbase = wave * 512;
      if (l == 0) {
        if (kbase < 1024) { src = (t == 0) ? xf16 : hbuf + (size_t)(2 + rp) * NBAT * HID; col0 = kbase; }
        else              { src = hbuf + (size_t)(0 + rp) * NBAT * HID; col0 = kbase - 1024; }
      } else {
        if (kbase < 1024) { src = hbuf + (size_t)(0 + wp) * NBAT * HID; col0 = kbase; }
        else              { src = hbuf + (size_t)(2 + rp) * NBAT * HID; col0 = kbase - 1024; }
      }
      const f16* r0 = src + (size_t)(l15 +  0) * HID + col0 + quad * 8;
      const f16* r1 = src + (size_t)(l15 + 16) * HID + col0 + quad * 8;
      const f16* r2 = src + (size_t)(l15 + 32) * HID + col0 + quad * 8;
      const f16* r3 = src + (size_t)(l15 + 48) * HID + col0 + quad * 8;

      // ---- MFMA: 16 gate-rows x 64 batch over this wave's K=512 ----
      int aoff = (l * 16 + l15) * AVEC + wave * 64 + quad;
      f32x4 a0 = {0.f, 0.f, 0.f, 0.f}, a1 = a0, a2 = a0, a3 = a0;
      #pragma unroll
      for (int kk = 0; kk < 16; ++kk) {
        f16x8 af  = Av[aoff + kk * 4];
        f16x8 b0v = ld16c(r0 + kk * 32);
        f16x8 b1v = ld16c(r1 + kk * 32);
        f16x8 b2v = ld16c(r2 + kk * 32);
        f16x8 b3v = ld16c(r3 + kk * 32);
        a0 = __builtin_amdgcn_mfma_f32_16x16x32_f16(af, b0v, a0, 0, 0, 0);
        a1 = __builtin_amdgcn_mfma_f32_16x16x32_f16(af, b1v, a1, 0, 0, 0);
        a2 = __builtin_amdgcn_mfma_f32_16x16x32_f16(af, b2v, a2, 0, 0, 0);
        a3 = __builtin_amdgcn_mfma_f32_16x16x32_f16(af, b3v, a3, 0, 0, 0);
      }
      // ---- partials to LDS scratch (C/D: col=lane&15, row=quad*4+reg) ----
      float* sc = scr + wave * 1024;
      #pragma unroll
      for (int r = 0; r < 4; ++r) {
        int base = (quad * 4 + r) * 64 + l15;
        sc[base +  0] = a0[r];
        sc[base + 16] = a1[r];
        sc[base + 32] = a2[r];
        sc[base + 48] = a3[r];
      }
      __syncthreads();

      // ---- elementwise: thread = (unit j, batch n); all gates CU-local ----
      {
        int j = tid >> 6, n = tid & 63;
        float gate[4];
        #pragma unroll
        for (int g = 0; g < 4; ++g) {
          int b0i = (g * 4 + j) * 64 + n;
          gate[g] = scr[b0i] + scr[1024 + b0i] + scr[2048 + b0i] + scr[3072 + b0i]
                  + biasS[l * 16 + g * 4 + j];
        }
        float cold = cS[l * 256 + j * 64 + n];
        float cn = sigm(gate[1]) * cold + sigm(gate[0]) * tanh_f(gate[2]);
        float hn = sigm(gate[3]) * tanh_f(cn);
        cS[l * 256 + j * 64 + n] = cn;
        hS[n * 4 + j] = (f16)hn;          // LDS transpose for coalesced store
      }
      __syncthreads();

      // ---- pack + coherent store: 8B h-store (+16B out on l==1), wave 0 only ----
      if (tid < 64) {
        int n = tid;
        union { u64 q; f16 h[4]; } pk;
        pk.q = *(const u64*)(hS + n * 4);
        st64c(hbuf + (size_t)(l * 2 + wp) * NBAT * HID + (size_t)n * HID + blk * 4, pk.q);
        if (l == 1) {
          union { u64 q; float f[2]; } o0, o1;
          o0.f[0] = (float)pk.h[0]; o0.f[1] = (float)pk.h[1];
          o1.f[0] = (float)pk.h[2]; o1.f[1] = (float)pk.h[3];
          float* op = out + (size_t)n * T * HID + (size_t)t * HID + blk * 4;
          st64c(op, o0.q);
          st64c(op + 2, o1.q);
        }
      }
      GRID_BARRIER();
    }
  }
}

extern "C" void kernel_launch(void* const* d_in, const int* in_sizes, int n_in,
                              void* d_out, int out_size, void* d_ws, size_t ws_size,
                              hipStream_t stream) {
  const float* x0  = (const float*)d_in[0];
  const float* h0  = (const float*)d_in[1];
  const float* c0  = (const float*)d_in[2];
  const float* Wih = (const float*)d_in[3];
  const float* Whh = (const float*)d_in[4];
  const float* bih = (const float*)d_in[5];
  const float* bhh = (const float*)d_in[6];
  const int* lenp  = (const int*)d_in[7];
  float* out = (float*)d_out;

  int* bar  = (int*)d_ws;
  f16* hbuf = (f16*)((char*)d_ws + 256);          // 4 x 64 x 1024 f16 = 512 KB
  f16* xbuf = hbuf + (size_t)4 * NBAT * HID;      // 64 x 1024 f16 = 128 KB

  hipFuncSetAttribute((const void*)lstm_kernel,
                      hipFuncAttributeMaxDynamicSharedMemorySize, LDS_BYTES);

  bar_init<<<1, 1, 0, stream>>>(bar);

  void* args[] = {&x0, &h0, &c0, &Wih, &Whh, &bih, &bhh, &lenp, &out, &bar, &hbuf, &xbuf};
  hipLaunchCooperativeKernel((void*)lstm_kernel, dim3(NBLK), dim3(NTHR),
                             args, LDS_BYTES, stream);
}

// Round 4
// 3680.795 us; speedup vs baseline: 5.0686x; 1.5234x over previous
//
#include <hip/hip_runtime.h>
#include <hip/hip_fp16.h>

#define HID   1024
#define NBAT  64
#define NBLK  256
#define NTHR  256
#define AROW  2056              // 2048 + 8 pad (f16 elems)
#define AVEC  257               // AROW/8

typedef _Float16 f16;
typedef unsigned long long u64;
typedef __attribute__((ext_vector_type(8))) _Float16 f16x8;
typedef __attribute__((ext_vector_type(4))) float f32x4;

// LDS layout (bytes)
#define A_BYTES   (2 * 16 * AROW * 2)    // 131584: weights, 2 layers x 16 rows x 2056 f16
#define SCR_OFF   A_BYTES                // f32 [4 kg][16 rows][64 batch] = 16384
#define C_OFF     (SCR_OFF + 16384)      // f32 [2 layers][4 units][64 batch] = 2048
#define BIAS_OFF  (C_OFF + 2048)         // f32 [2][16] = 128
#define HS_OFF    (BIAS_OFF + 128)       // f16 [64 batch][4 units] = 512
#define LDS_BYTES (HS_OFF + 512)         // 150656 < 160 KiB

// barrier layout in ws (ints, 64B-spaced slots): leaf i at [16*i] (i<16),
// root count at [16*16], released epoch at [16*17]
#define BAR_INTS  (16 * 18)

__device__ __forceinline__ float sigm(float x) { return 1.f / (1.f + __expf(-x)); }
__device__ __forceinline__ float tanh_f(float x) {
  float xc = fminf(fmaxf(x, -10.f), 10.f);
  float e = __expf(2.f * xc);
  return (e - 1.f) / (e + 1.f);
}

// Coherent write: agent-scope relaxed atomic store => sc1 write-through to MALL,
// no cache-maintenance ops emitted.
__device__ __forceinline__ void st64c(void* p, u64 v) {
  __hip_atomic_store((u64*)p, v, __ATOMIC_RELAXED, __HIP_MEMORY_SCOPE_AGENT);
}

__global__ void bar_init(int* bar) { if (threadIdx.x < BAR_INTS) bar[threadIdx.x] = 0; }

// Block b owns hidden units [4b,4b+4) for both layers.
// LDS weight row m = g*4 + j (gate g in {i,f,g,o}, unit j in 0..3),
// fused K: [W_ih row (1024) | W_hh row (1024)], stored f16.
// hbuf: f16 [layer][parity][64][1024], double-buffered by step parity.
// h/x/out stores: sc1 write-through (MALL always fresh at barrier release).
// B reads: PLAIN cached loads, made safe by one agent acquire fence
// (buffer_inv sc1: drops L1+L2) per block per phase, after release, before loads.
// => 32 CUs/XCD share one L2 fill of the 256KB B tile instead of 32 MALL pulls.
__global__ __launch_bounds__(NTHR, 1) void lstm_kernel(
    const float* __restrict__ x0, const float* __restrict__ h0,
    const float* __restrict__ c0, const float* __restrict__ Wih,
    const float* __restrict__ Whh, const float* __restrict__ bih,
    const float* __restrict__ bhh, const int* __restrict__ lenp,
    float* __restrict__ out, int* __restrict__ bar,
    f16* __restrict__ hbuf, f16* __restrict__ xf16)
{
  extern __shared__ char smem[];
  f16*   Alds  = (f16*)smem;
  float* scr   = (float*)(smem + SCR_OFF);
  float* cS    = (float*)(smem + C_OFF);
  float* biasS = (float*)(smem + BIAS_OFF);
  f16*   hS    = (f16*)(smem + HS_OFF);     // [n][j] transpose buffer

  const int tid  = threadIdx.x;
  const int blk  = blockIdx.x;
  const int wave = tid >> 6;
  const int lane = tid & 63;
  const int quad = lane >> 4;
  const int l15  = lane & 15;
  const int T    = *lenp;

  int* leaf   = bar + 16 * (blk & 15);
  int* rootc  = bar + 16 * 16;
  int* epochw = bar + 16 * 17;

  // ---- stage weights (f32 -> f16) into LDS: 64 rows-of-1024, 4 threads/row ----
  {
    int r    = tid >> 2;            // 0..63
    int part = tid & 3;             // 256-elem chunk within the 1024-row
    int l    = r >> 5;
    int m    = (r >> 1) & 15;
    int half = r & 1;               // 0: W_ih, 1: W_hh
    int g    = m >> 2, j = m & 3;
    size_t grow = (size_t)g * HID + blk * 4 + j;
    const float* srcW = (half ? Whh : Wih) + ((size_t)l * 4 * HID + grow) * HID + part * 256;
    f16x8* dst = (f16x8*)(Alds + (size_t)(l * 16 + m) * AROW + half * HID + part * 256);
    const float4* s4 = (const float4*)srcW;
    #pragma unroll 4
    for (int i = 0; i < 32; ++i) {
      float4 w0 = s4[2 * i], w1 = s4[2 * i + 1];
      f16x8 o = {(f16)w0.x, (f16)w0.y, (f16)w0.z, (f16)w0.w,
                 (f16)w1.x, (f16)w1.y, (f16)w1.z, (f16)w1.w};
      dst[i] = o;
    }
  }
  // ---- biases (b_ih + b_hh, fp32) ----
  if (tid < 32) {
    int l = tid >> 4, m = tid & 15;
    int g = m >> 2, j = m & 3;
    size_t row = (size_t)g * HID + blk * 4 + j;
    biasS[l * 16 + m] = bih[(size_t)l * 4 * HID + row] + bhh[(size_t)l * 4 * HID + row];
  }
  // ---- c state (fp32, CU-local forever) ----
  {
    int j = tid >> 6, n = tid & 63;
    #pragma unroll
    for (int l = 0; l < 2; ++l)
      cS[l * 256 + j * 64 + n] =
          c0[(size_t)l * NBAT * HID + (size_t)n * HID + blk * 4 + j];
  }
  // ---- h0 -> hbuf parity 1 (sc1, 8B coalesced) ----
  if (tid < 128) {
    int l = tid >> 6, n = tid & 63;
    const float* hp = h0 + (size_t)l * NBAT * HID + (size_t)n * HID + blk * 4;
    union { u64 q; f16 h[4]; } pk;
    pk.h[0] = (f16)hp[0]; pk.h[1] = (f16)hp[1]; pk.h[2] = (f16)hp[2]; pk.h[3] = (f16)hp[3];
    st64c(hbuf + (size_t)(l * 2 + 1) * NBAT * HID + (size_t)n * HID + blk * 4, pk.q);
  }
  // ---- x0 -> f16 (sc1): blocks 0..63 stage 1024 elems each ----
  if (blk < 64) {
    const float* xp = x0 + (size_t)blk * 1024 + tid * 4;
    union { u64 q; f16 h[4]; } pk;
    pk.h[0] = (f16)xp[0]; pk.h[1] = (f16)xp[1]; pk.h[2] = (f16)xp[2]; pk.h[3] = (f16)xp[3];
    st64c(xf16 + (size_t)blk * 1024 + tid * 4, pk.q);
  }

  // ---- two-level grid barrier: 16 leaves x 16 blocks -> root -> epoch ----
  // Monotone counters (no resets). Acquire fence (buffer_inv sc1) after release
  // makes subsequent PLAIN loads coherent with pre-barrier sc1 stores.
  int epoch = 1;
  #define GRID_BARRIER()                                                          \
    do {                                                                          \
      asm volatile("s_waitcnt vmcnt(0)" ::: "memory");                            \
      __syncthreads();                                                            \
      if (tid == 0) {                                                             \
        int prev = __hip_atomic_fetch_add(leaf, 1, __ATOMIC_RELAXED,              \
                                          __HIP_MEMORY_SCOPE_AGENT);              \
        bool released = false;                                                    \
        if (prev == 16 * epoch - 1) {                                             \
          int rprev = __hip_atomic_fetch_add(rootc, 1, __ATOMIC_RELAXED,          \
                                             __HIP_MEMORY_SCOPE_AGENT);          \
          if (rprev == 16 * epoch - 1) {                                          \
            __hip_atomic_store(epochw, epoch, __ATOMIC_RELAXED,                   \
                               __HIP_MEMORY_SCOPE_AGENT);                         \
            released = true;                                                      \
          }                                                                       \
        }                                                                         \
        if (!released) {                                                          \
          while (__hip_atomic_load(epochw, __ATOMIC_RELAXED,                      \
                                   __HIP_MEMORY_SCOPE_AGENT) < epoch)             \
            __builtin_amdgcn_s_sleep(2);                                          \
        }                                                                         \
        __builtin_amdgcn_fence(__ATOMIC_ACQUIRE, "agent"); /* buffer_inv sc1 */   \
      }                                                                           \
      epoch++;                                                                    \
      __syncthreads();                                                            \
    } while (0)

  GRID_BARRIER();

  const f16x8* Av = (const f16x8*)Alds;

  for (int t = 0; t < T; ++t) {
    const int wp = t & 1, rp = wp ^ 1;
    #pragma unroll 1
    for (int l = 0; l < 2; ++l) {
      // ---- B source for this wave's K-quarter ----
      const f16* src; int col0;
      const int kbase = wave * 512;
      if (l == 0) {
        if (kbase < 1024) { src = (t == 0) ? xf16 : hbuf + (size_t)(2 + rp) * NBAT * HID; col0 = kbase; }
        else              { src = hbuf + (size_t)(0 + rp) * NBAT * HID; col0 = kbase - 1024; }
      } else {
        if (kbase < 1024) { src = hbuf + (size_t)(0 + wp) * NBAT * HID; col0 = kbase; }
        else              { src = hbuf + (size_t)(2 + rp) * NBAT * HID; col0 = kbase - 1024; }
      }
      const f16* r0 = src + (size_t)(l15 +  0) * HID + col0 + quad * 8;
      const f16* r1 = src + (size_t)(l15 + 16) * HID + col0 + quad * 8;
      const f16* r2 = src + (size_t)(l15 + 32) * HID + col0 + quad * 8;
      const f16* r3 = src + (size_t)(l15 + 48) * HID + col0 + quad * 8;

      // ---- MFMA: 16 gate-rows x 64 batch over this wave's K=512 ----
      // B loads are plain cached loads (L2-shared across the XCD's CUs).
      int aoff = (l * 16 + l15) * AVEC + wave * 64 + quad;
      f32x4 a0 = {0.f, 0.f, 0.f, 0.f}, a1 = a0, a2 = a0, a3 = a0;
      #pragma unroll
      for (int kk = 0; kk < 16; ++kk) {
        f16x8 af  = Av[aoff + kk * 4];
        f16x8 b0v = *(const f16x8*)(r0 + kk * 32);
        f16x8 b1v = *(const f16x8*)(r1 + kk * 32);
        f16x8 b2v = *(const f16x8*)(r2 + kk * 32);
        f16x8 b3v = *(const f16x8*)(r3 + kk * 32);
        a0 = __builtin_amdgcn_mfma_f32_16x16x32_f16(af, b0v, a0, 0, 0, 0);
        a1 = __builtin_amdgcn_mfma_f32_16x16x32_f16(af, b1v, a1, 0, 0, 0);
        a2 = __builtin_amdgcn_mfma_f32_16x16x32_f16(af, b2v, a2, 0, 0, 0);
        a3 = __builtin_amdgcn_mfma_f32_16x16x32_f16(af, b3v, a3, 0, 0, 0);
      }
      // ---- partials to LDS scratch (C/D: col=lane&15, row=quad*4+reg) ----
      float* sc = scr + wave * 1024;
      #pragma unroll
      for (int r = 0; r < 4; ++r) {
        int base = (quad * 4 + r) * 64 + l15;
        sc[base +  0] = a0[r];
        sc[base + 16] = a1[r];
        sc[base + 32] = a2[r];
        sc[base + 48] = a3[r];
      }
      __syncthreads();

      // ---- elementwise: thread = (unit j, batch n); all gates CU-local ----
      {
        int j = tid >> 6, n = tid & 63;
        float gate[4];
        #pragma unroll
        for (int g = 0; g < 4; ++g) {
          int b0i = (g * 4 + j) * 64 + n;
          gate[g] = scr[b0i] + scr[1024 + b0i] + scr[2048 + b0i] + scr[3072 + b0i]
                  + biasS[l * 16 + g * 4 + j];
        }
        float cold = cS[l * 256 + j * 64 + n];
        float cn = sigm(gate[1]) * cold + sigm(gate[0]) * tanh_f(gate[2]);
        float hn = sigm(gate[3]) * tanh_f(cn);
        cS[l * 256 + j * 64 + n] = cn;
        hS[n * 4 + j] = (f16)hn;          // LDS transpose for coalesced store
      }
      __syncthreads();

      // ---- pack + coherent store: 8B h-store (+16B out on l==1), wave 0 only ----
      if (tid < 64) {
        int n = tid;
        union { u64 q; f16 h[4]; } pk;
        pk.q = *(const u64*)(hS + n * 4);
        st64c(hbuf + (size_t)(l * 2 + wp) * NBAT * HID + (size_t)n * HID + blk * 4, pk.q);
        if (l == 1) {
          union { u64 q; float f[2]; } o0, o1;
          o0.f[0] = (float)pk.h[0]; o0.f[1] = (float)pk.h[1];
          o1.f[0] = (float)pk.h[2]; o1.f[1] = (float)pk.h[3];
          float* op = out + (size_t)n * T * HID + (size_t)t * HID + blk * 4;
          st64c(op, o0.q);
          st64c(op + 2, o1.q);
        }
      }
      GRID_BARRIER();
    }
  }
}

extern "C" void kernel_launch(void* const* d_in, const int* in_sizes, int n_in,
                              void* d_out, int out_size, void* d_ws, size_t ws_size,
                              hipStream_t stream) {
  const float* x0  = (const float*)d_in[0];
  const float* h0  = (const float*)d_in[1];
  const float* c0  = (const float*)d_in[2];
  const float* Wih = (const float*)d_in[3];
  const float* Whh = (const float*)d_in[4];
  const float* bih = (const float*)d_in[5];
  const float* bhh = (const float*)d_in[6];
  const int* lenp  = (const int*)d_in[7];
  float* out = (float*)d_out;

  int* bar  = (int*)d_ws;
  f16* hbuf = (f16*)((char*)d_ws + 4096);         // 4 x 64 x 1024 f16 = 512 KB
  f16* xbuf = hbuf + (size_t)4 * NBAT * HID;      // 64 x 1024 f16 = 128 KB

  hipFuncSetAttribute((const void*)lstm_kernel,
                      hipFuncAttributeMaxDynamicSharedMemorySize, LDS_BYTES);

  bar_init<<<1, 512, 0, stream>>>(bar);

  void* args[] = {&x0, &h0, &c0, &Wih, &Whh, &bih, &bhh, &lenp, &out, &bar, &hbuf, &xbuf};
  hipLaunchCooperativeKernel((void*)lstm_kernel, dim3(NBLK), dim3(NTHR),
                             args, LDS_BYTES, stream);
}

// Round 5
// 3282.934 us; speedup vs baseline: 5.6829x; 1.1212x over previous
//
#include <hip/hip_runtime.h>
#include <hip/hip_fp16.h>

#define HID   1024
#define NBAT  64
#define NBLK  256
#define NTHR  256
#define AROW  2056              // 2048 + 8 pad (f16 elems)
#define AVEC  257               // AROW/8

typedef _Float16 f16;
typedef unsigned long long u64;
typedef __attribute__((ext_vector_type(8))) _Float16 f16x8;
typedef __attribute__((ext_vector_type(4))) float f32x4;

// LDS layout (bytes)
#define A_BYTES   (2 * 16 * AROW * 2)    // 131584: weights, 2 layers x 16 rows x 2056 f16
#define SCR_OFF   A_BYTES                // f32 [4 kg][16 rows][64 batch] = 16384
#define C_OFF     (SCR_OFF + 16384)      // f32 [2 layers][4 units][64 batch] = 2048
#define BIAS_OFF  (C_OFF + 2048)         // f32 [2][16] = 128
#define HS_OFF    (BIAS_OFF + 128)       // f16 [64 batch][4 units] = 512
#define LDS_BYTES (HS_OFF + 512)         // 150656 < 160 KiB

// barrier layout in ws (ints, 256B-spaced slots to spread MALL channels):
//   leaf i count   : bar[64*i]        i in [0,16)
//   root count     : bar[64*16]
//   release flag i : bar[64*(17+i)]   i in [0,16)
#define BAR_INTS  (64 * 33)             // 8448 B < 16 KB reserved

__device__ __forceinline__ float sigm(float x) { return 1.f / (1.f + __expf(-x)); }
__device__ __forceinline__ float tanh_f(float x) {
  float xc = fminf(fmaxf(x, -10.f), 10.f);
  float e = __expf(2.f * xc);
  return (e - 1.f) / (e + 1.f);
}

// Coherent write: agent-scope relaxed atomic store => sc1 write-through to MALL,
// no cache-maintenance ops emitted.
__device__ __forceinline__ void st64c(void* p, u64 v) {
  __hip_atomic_store((u64*)p, v, __ATOMIC_RELAXED, __HIP_MEMORY_SCOPE_AGENT);
}
__device__ __forceinline__ void st32c(int* p, int v) {
  __hip_atomic_store(p, v, __ATOMIC_RELAXED, __HIP_MEMORY_SCOPE_AGENT);
}

__global__ void bar_init(int* bar) {
  int i = threadIdx.x;
  #pragma unroll
  for (int k = 0; k < 9; ++k) {           // 1024 threads x 9 >= 8448/4
    int idx = i + k * 1024;
    if (idx < BAR_INTS) bar[idx] = 0;
  }
}

// Block b owns hidden units [4b,4b+4) for both layers.
// LDS weight row m = g*4 + j (gate g in {i,f,g,o}, unit j in 0..3),
// fused K: [W_ih row (1024) | W_hh row (1024)], stored f16.
// hbuf: f16 [layer][parity][64][1024], double-buffered by step parity.
// h/x/out stores: sc1 write-through (MALL fresh when counted at the barrier,
// because each block drains vmcnt(0) BEFORE its leaf arrival RMW).
// B reads: plain cached loads; one agent acquire fence (buffer_inv sc1:
// drops L1+XCD-L2) per block per phase, after release, before loads
// => 32 CUs/XCD share one L2 fill of the B tile.
__global__ __launch_bounds__(NTHR, 1) void lstm_kernel(
    const float* __restrict__ x0, const float* __restrict__ h0,
    const float* __restrict__ c0, const float* __restrict__ Wih,
    const float* __restrict__ Whh, const float* __restrict__ bih,
    const float* __restrict__ bhh, const int* __restrict__ lenp,
    float* __restrict__ out, int* __restrict__ bar,
    f16* __restrict__ hbuf, f16* __restrict__ xf16)
{
  extern __shared__ char smem[];
  f16*   Alds  = (f16*)smem;
  float* scr   = (float*)(smem + SCR_OFF);
  float* cS    = (float*)(smem + C_OFF);
  float* biasS = (float*)(smem + BIAS_OFF);
  f16*   hS    = (f16*)(smem + HS_OFF);     // [n][j] transpose buffer

  const int tid  = threadIdx.x;
  const int blk  = blockIdx.x;
  const int wave = tid >> 6;
  const int lane = tid & 63;
  const int quad = lane >> 4;
  const int l15  = lane & 15;
  const int T    = *lenp;

  const int leafid = blk & 15;
  int* leaf    = bar + 64 * leafid;
  int* rootc   = bar + 64 * 16;
  int* relme   = bar + 64 * (17 + leafid);

  // ---- stage weights (f32 -> f16) into LDS: 64 rows-of-1024, 4 threads/row ----
  {
    int r    = tid >> 2;            // 0..63
    int part = tid & 3;             // 256-elem chunk within the 1024-row
    int l    = r >> 5;
    int m    = (r >> 1) & 15;
    int half = r & 1;               // 0: W_ih, 1: W_hh
    int g    = m >> 2, j = m & 3;
    size_t grow = (size_t)g * HID + blk * 4 + j;
    const float* srcW = (half ? Whh : Wih) + ((size_t)l * 4 * HID + grow) * HID + part * 256;
    f16x8* dst = (f16x8*)(Alds + (size_t)(l * 16 + m) * AROW + half * HID + part * 256);
    const float4* s4 = (const float4*)srcW;
    #pragma unroll 4
    for (int i = 0; i < 32; ++i) {
      float4 w0 = s4[2 * i], w1 = s4[2 * i + 1];
      f16x8 o = {(f16)w0.x, (f16)w0.y, (f16)w0.z, (f16)w0.w,
                 (f16)w1.x, (f16)w1.y, (f16)w1.z, (f16)w1.w};
      dst[i] = o;
    }
  }
  // ---- biases (b_ih + b_hh, fp32) ----
  if (tid < 32) {
    int l = tid >> 4, m = tid & 15;
    int g = m >> 2, j = m & 3;
    size_t row = (size_t)g * HID + blk * 4 + j;
    biasS[l * 16 + m] = bih[(size_t)l * 4 * HID + row] + bhh[(size_t)l * 4 * HID + row];
  }
  // ---- c state (fp32, CU-local forever) ----
  {
    int j = tid >> 6, n = tid & 63;
    #pragma unroll
    for (int l = 0; l < 2; ++l)
      cS[l * 256 + j * 64 + n] =
          c0[(size_t)l * NBAT * HID + (size_t)n * HID + blk * 4 + j];
  }
  // ---- h0 -> hbuf parity 1 (sc1, 8B coalesced) ----
  if (tid < 128) {
    int l = tid >> 6, n = tid & 63;
    const float* hp = h0 + (size_t)l * NBAT * HID + (size_t)n * HID + blk * 4;
    union { u64 q; f16 h[4]; } pk;
    pk.h[0] = (f16)hp[0]; pk.h[1] = (f16)hp[1]; pk.h[2] = (f16)hp[2]; pk.h[3] = (f16)hp[3];
    st64c(hbuf + (size_t)(l * 2 + 1) * NBAT * HID + (size_t)n * HID + blk * 4, pk.q);
  }
  // ---- x0 -> f16 (sc1): blocks 0..63 stage 1024 elems each ----
  if (blk < 64) {
    const float* xp = x0 + (size_t)blk * 1024 + tid * 4;
    union { u64 q; f16 h[4]; } pk;
    pk.h[0] = (f16)xp[0]; pk.h[1] = (f16)xp[1]; pk.h[2] = (f16)xp[2]; pk.h[3] = (f16)xp[3];
    st64c(xf16 + (size_t)blk * 1024 + tid * 4, pk.q);
  }

  // ---- two-level grid barrier with FAN-OUT release ----
  // Arrival: 16 leaf counters (256B apart) -> root. Release: root winner writes
  // 16 per-leaf flags; each block polls ONLY its leaf's flag (<=16 pollers/line)
  // => no single-line poll convoy. All counters monotone. Acquire fence
  // (buffer_inv sc1) after release covers L1+L2 staleness for plain B loads.
  int epoch = 1;
  #define GRID_BARRIER()                                                          \
    do {                                                                          \
      asm volatile("s_waitcnt vmcnt(0)" ::: "memory");                            \
      __syncthreads();                                                            \
      if (tid == 0) {                                                             \
        int prev = __hip_atomic_fetch_add(leaf, 1, __ATOMIC_RELAXED,              \
                                          __HIP_MEMORY_SCOPE_AGENT);              \
        bool released = false;                                                    \
        if (prev == 16 * epoch - 1) {                                             \
          int rprev = __hip_atomic_fetch_add(rootc, 1, __ATOMIC_RELAXED,          \
                                             __HIP_MEMORY_SCOPE_AGENT);          \
          if (rprev == 16 * epoch - 1) {                                          \
            _Pragma("unroll")                                                     \
            for (int i = 0; i < 16; ++i)                                          \
              st32c(bar + 64 * (17 + i), epoch);                                  \
            released = true;                                                      \
          }                                                                       \
        }                                                                         \
        if (!released) {                                                          \
          while (__hip_atomic_load(relme, __ATOMIC_RELAXED,                       \
                                   __HIP_MEMORY_SCOPE_AGENT) < epoch)             \
            __builtin_amdgcn_s_sleep(4);                                          \
        }                                                                         \
        __builtin_amdgcn_fence(__ATOMIC_ACQUIRE, "agent"); /* buffer_inv sc1 */   \
      }                                                                           \
      epoch++;                                                                    \
      __syncthreads();                                                            \
    } while (0)

  GRID_BARRIER();

  const f16x8* Av = (const f16x8*)Alds;

  for (int t = 0; t < T; ++t) {
    const int wp = t & 1, rp = wp ^ 1;
    #pragma unroll 1
    for (int l = 0; l < 2; ++l) {
      // ---- B source for this wave's K-quarter ----
      const f16* src; int col0;
      const int kbase = wave * 512;
      if (l == 0) {
        if (kbase < 1024) { src = (t == 0) ? xf16 : hbuf + (size_t)(2 + rp) * NBAT * HID; col0 = kbase; }
        else              { src = hbuf + (size_t)(0 + rp) * NBAT * HID; col0 = kbase - 1024; }
      } else {
        if (kbase < 1024) { src = hbuf + (size_t)(0 + wp) * NBAT * HID; col0 = kbase; }
        else              { src = hbuf + (size_t)(2 + rp) * NBAT * HID; col0 = kbase - 1024; }
      }
      const f16* r0 = src + (size_t)(l15 +  0) * HID + col0 + quad * 8;
      const f16* r1 = src + (size_t)(l15 + 16) * HID + col0 + quad * 8;
      const f16* r2 = src + (size_t)(l15 + 32) * HID + col0 + quad * 8;
      const f16* r3 = src + (size_t)(l15 + 48) * HID + col0 + quad * 8;

      // ---- MFMA: 16 gate-rows x 64 batch over this wave's K=512 ----
      int aoff = (l * 16 + l15) * AVEC + wave * 64 + quad;
      f32x4 a0 = {0.f, 0.f, 0.f, 0.f}, a1 = a0, a2 = a0, a3 = a0;
      #pragma unroll
      for (int kk = 0; kk < 16; ++kk) {
        f16x8 af  = Av[aoff + kk * 4];
        f16x8 b0v = *(const f16x8*)(r0 + kk * 32);
        f16x8 b1v = *(const f16x8*)(r1 + kk * 32);
        f16x8 b2v = *(const f16x8*)(r2 + kk * 32);
        f16x8 b3v = *(const f16x8*)(r3 + kk * 32);
        a0 = __builtin_amdgcn_mfma_f32_16x16x32_f16(af, b0v, a0, 0, 0, 0);
        a1 = __builtin_amdgcn_mfma_f32_16x16x32_f16(af, b1v, a1, 0, 0, 0);
        a2 = __builtin_amdgcn_mfma_f32_16x16x32_f16(af, b2v, a2, 0, 0, 0);
        a3 = __builtin_amdgcn_mfma_f32_16x16x32_f16(af, b3v, a3, 0, 0, 0);
      }
      // ---- partials to LDS scratch (C/D: col=lane&15, row=quad*4+reg) ----
      float* sc = scr + wave * 1024;
      #pragma unroll
      for (int r = 0; r < 4; ++r) {
        int base = (quad * 4 + r) * 64 + l15;
        sc[base +  0] = a0[r];
        sc[base + 16] = a1[r];
        sc[base + 32] = a2[r];
        sc[base + 48] = a3[r];
      }
      __syncthreads();

      // ---- elementwise: thread = (unit j, batch n); all gates CU-local ----
      {
        int j = tid >> 6, n = tid & 63;
        float gate[4];
        #pragma unroll
        for (int g = 0; g < 4; ++g) {
          int b0i = (g * 4 + j) * 64 + n;
          gate[g] = scr[b0i] + scr[1024 + b0i] + scr[2048 + b0i] + scr[3072 + b0i]
                  + biasS[l * 16 + g * 4 + j];
        }
        float cold = cS[l * 256 + j * 64 + n];
        float cn = sigm(gate[1]) * cold + sigm(gate[0]) * tanh_f(gate[2]);
        float hn = sigm(gate[3]) * tanh_f(cn);
        cS[l * 256 + j * 64 + n] = cn;
        hS[n * 4 + j] = (f16)hn;          // LDS transpose for coalesced store
      }
      __syncthreads();

      // ---- pack + coherent store: 8B h-store (+16B out on l==1), wave 0 only ----
      if (tid < 64) {
        int n = tid;
        union { u64 q; f16 h[4]; } pk;
        pk.q = *(const u64*)(hS + n * 4);
        st64c(hbuf + (size_t)(l * 2 + wp) * NBAT * HID + (size_t)n * HID + blk * 4, pk.q);
        if (l == 1) {
          union { u64 q; float f[2]; } o0, o1;
          o0.f[0] = (float)pk.h[0]; o0.f[1] = (float)pk.h[1];
          o1.f[0] = (float)pk.h[2]; o1.f[1] = (float)pk.h[3];
          float* op = out + (size_t)n * T * HID + (size_t)t * HID + blk * 4;
          st64c(op, o0.q);
          st64c(op + 2, o1.q);
        }
      }
      GRID_BARRIER();
    }
  }
}

extern "C" void kernel_launch(void* const* d_in, const int* in_sizes, int n_in,
                              void* d_out, int out_size, void* d_ws, size_t ws_size,
                              hipStream_t stream) {
  const float* x0  = (const float*)d_in[0];
  const float* h0  = (const float*)d_in[1];
  const float* c0  = (const float*)d_in[2];
  const float* Wih = (const float*)d_in[3];
  const float* Whh = (const float*)d_in[4];
  const float* bih = (const float*)d_in[5];
  const float* bhh = (const float*)d_in[6];
  const int* lenp  = (const int*)d_in[7];
  float* out = (float*)d_out;

  int* bar  = (int*)d_ws;
  f16* hbuf = (f16*)((char*)d_ws + 16384);        // 4 x 64 x 1024 f16 = 512 KB
  f16* xbuf = hbuf + (size_t)4 * NBAT * HID;      // 64 x 1024 f16 = 128 KB

  hipFuncSetAttribute((const void*)lstm_kernel,
                      hipFuncAttributeMaxDynamicSharedMemorySize, LDS_BYTES);

  bar_init<<<1, 1024, 0, stream>>>(bar);

  void* args[] = {&x0, &h0, &c0, &Wih, &Whh, &bih, &bhh, &lenp, &out, &bar, &hbuf, &xbuf};
  hipLaunchCooperativeKernel((void*)lstm_kernel, dim3(NBLK), dim3(NTHR),
                             args, LDS_BYTES, stream);
}

// Round 6
// 2952.180 us; speedup vs baseline: 6.3196x; 1.1120x over previous
//
#include <hip/hip_runtime.h>
#include <hip/hip_fp16.h>

#define HID   1024
#define NBAT  64
#define NBLK  256
#define NTHR  256
#define AROW  2056              // 2048 + 8 pad (f16 elems)
#define AVEC  257               // AROW/8

typedef _Float16 f16;
typedef unsigned long long u64;
typedef __attribute__((ext_vector_type(8))) _Float16 f16x8;
typedef __attribute__((ext_vector_type(4))) float f32x4;

// LDS layout (bytes)
#define A_BYTES   (2 * 16 * AROW * 2)    // 131584: weights, 2 layers x 16 rows x 2056 f16
#define SCR_OFF   A_BYTES                // f32 [4 kg][16 rows][64 batch] = 16384
#define C_OFF     (SCR_OFF + 16384)      // f32 [2 layers][4 units][64 batch] = 2048
#define BIAS_OFF  (C_OFF + 2048)         // f32 [2][16] = 128
#define HS_OFF    (BIAS_OFF + 128)       // f16 [64 batch][4 units] = 512
#define LDS_BYTES (HS_OFF + 512)         // 150656 < 160 KiB

// barrier layout in ws (ints, 256B-spaced slots to spread MALL channels):
//   leaf i count   : bar[64*i]         i in [0,16)
//   root count     : bar[64*16]
//   release flag i : bar[64*(17+i)]    i in [0,16)
//   xcd elect cnt x: bar[64*(33+x)]    x in [0,8)
//   xcd inv flag x : bar[64*(41+x)]    x in [0,8)
#define BAR_INTS  (64 * 49)             // 12544 B < 16 KB reserved

__device__ __forceinline__ float sigm(float x) { return 1.f / (1.f + __expf(-x)); }
__device__ __forceinline__ float tanh_f(float x) {
  float xc = fminf(fmaxf(x, -10.f), 10.f);
  float e = __expf(2.f * xc);
  return (e - 1.f) / (e + 1.f);
}

// Coherent access: agent-scope relaxed atomics => sc1 (bypass L1/L2, hit MALL),
// no cache-maintenance ops emitted.
__device__ __forceinline__ void st64c(void* p, u64 v) {
  __hip_atomic_store((u64*)p, v, __ATOMIC_RELAXED, __HIP_MEMORY_SCOPE_AGENT);
}
__device__ __forceinline__ void st32c(int* p, int v) {
  __hip_atomic_store(p, v, __ATOMIC_RELAXED, __HIP_MEMORY_SCOPE_AGENT);
}
__device__ __forceinline__ int ld32c(const int* p) {
  return __hip_atomic_load(p, __ATOMIC_RELAXED, __HIP_MEMORY_SCOPE_AGENT);
}

__global__ void bar_init(int* bar) {
  int i = threadIdx.x;
  #pragma unroll
  for (int k = 0; k < 4; ++k) {
    int idx = i + k * 1024;
    if (idx < BAR_INTS) bar[idx] = 0;
  }
}

// Block b owns hidden units [4b,4b+4) for both layers.
// Weights cached in LDS (f16) for the whole kernel. hbuf: f16
// [layer][parity][64][1024], double-buffered by step parity.
// h/x/out stores: sc1 write-through (in MALL before the arrival RMW, since each
// block drains vmcnt(0) first). B reads: plain cached loads, made coherent by
// ONE buffer_inv sc1 per XCD per phase (leader-elected via HW_REG_XCC_ID),
// ordered via per-XCD invflag. Per-CU L1 staleness is impossible: 256KB of B
// streams through the 32KB L1 every phase, evicting everything.
__global__ __launch_bounds__(NTHR, 1) void lstm_kernel(
    const float* __restrict__ x0, const float* __restrict__ h0,
    const float* __restrict__ c0, const float* __restrict__ Wih,
    const float* __restrict__ Whh, const float* __restrict__ bih,
    const float* __restrict__ bhh, const int* __restrict__ lenp,
    float* __restrict__ out, int* __restrict__ bar,
    f16* __restrict__ hbuf, f16* __restrict__ xf16)
{
  extern __shared__ char smem[];
  f16*   Alds  = (f16*)smem;
  float* scr   = (float*)(smem + SCR_OFF);
  float* cS    = (float*)(smem + C_OFF);
  float* biasS = (float*)(smem + BIAS_OFF);
  f16*   hS    = (f16*)(smem + HS_OFF);     // [n][j] transpose buffer

  const int tid  = threadIdx.x;
  const int blk  = blockIdx.x;
  const int wave = tid >> 6;
  const int lane = tid & 63;
  const int quad = lane >> 4;
  const int l15  = lane & 15;
  const int T    = *lenp;

  const int leafid = blk & 15;
  int* leaf    = bar + 64 * leafid;
  int* rootc   = bar + 64 * 16;
  int* relme   = bar + 64 * (17 + leafid);

  // ---- physical XCD id + one-time leader election ----
  unsigned xcc;
  asm volatile("s_getreg_b32 %0, hwreg(HW_REG_XCC_ID)" : "=s"(xcc));
  xcc &= 7;
  int* invflag = bar + 64 * (41 + xcc);
  int is_leader = 0;
  if (tid == 0) {
    int p = __hip_atomic_fetch_add(bar + 64 * (33 + xcc), 1, __ATOMIC_RELAXED,
                                   __HIP_MEMORY_SCOPE_AGENT);
    is_leader = (p == 0);
  }

  // ---- stage weights (f32 -> f16) into LDS: 64 rows-of-1024, 4 threads/row ----
  {
    int r    = tid >> 2;            // 0..63
    int part = tid & 3;             // 256-elem chunk within the 1024-row
    int l    = r >> 5;
    int m    = (r >> 1) & 15;
    int half = r & 1;               // 0: W_ih, 1: W_hh
    int g    = m >> 2, j = m & 3;
    size_t grow = (size_t)g * HID + blk * 4 + j;
    const float* srcW = (half ? Whh : Wih) + ((size_t)l * 4 * HID + grow) * HID + part * 256;
    f16x8* dst = (f16x8*)(Alds + (size_t)(l * 16 + m) * AROW + half * HID + part * 256);
    const float4* s4 = (const float4*)srcW;
    #pragma unroll 4
    for (int i = 0; i < 32; ++i) {
      float4 w0 = s4[2 * i], w1 = s4[2 * i + 1];
      f16x8 o = {(f16)w0.x, (f16)w0.y, (f16)w0.z, (f16)w0.w,
                 (f16)w1.x, (f16)w1.y, (f16)w1.z, (f16)w1.w};
      dst[i] = o;
    }
  }
  // ---- biases (b_ih + b_hh, fp32) ----
  if (tid < 32) {
    int l = tid >> 4, m = tid & 15;
    int g = m >> 2, j = m & 3;
    size_t row = (size_t)g * HID + blk * 4 + j;
    biasS[l * 16 + m] = bih[(size_t)l * 4 * HID + row] + bhh[(size_t)l * 4 * HID + row];
  }
  // ---- c state (fp32, CU-local forever) ----
  {
    int j = tid >> 6, n = tid & 63;
    #pragma unroll
    for (int l = 0; l < 2; ++l)
      cS[l * 256 + j * 64 + n] =
          c0[(size_t)l * NBAT * HID + (size_t)n * HID + blk * 4 + j];
  }
  // ---- h0 -> hbuf parity 1 (sc1, 8B coalesced) ----
  if (tid < 128) {
    int l = tid >> 6, n = tid & 63;
    const float* hp = h0 + (size_t)l * NBAT * HID + (size_t)n * HID + blk * 4;
    union { u64 q; f16 h[4]; } pk;
    pk.h[0] = (f16)hp[0]; pk.h[1] = (f16)hp[1]; pk.h[2] = (f16)hp[2]; pk.h[3] = (f16)hp[3];
    st64c(hbuf + (size_t)(l * 2 + 1) * NBAT * HID + (size_t)n * HID + blk * 4, pk.q);
  }
  // ---- x0 -> f16 (sc1): blocks 0..63 stage 1024 elems each ----
  if (blk < 64) {
    const float* xp = x0 + (size_t)blk * 1024 + tid * 4;
    union { u64 q; f16 h[4]; } pk;
    pk.h[0] = (f16)xp[0]; pk.h[1] = (f16)xp[1]; pk.h[2] = (f16)xp[2]; pk.h[3] = (f16)xp[3];
    st64c(xf16 + (size_t)blk * 1024 + tid * 4, pk.q);
  }

  // ---- grid barrier: tree arrival, fan-out release, per-XCD single inv ----
  int epoch = 1;
  #define GRID_BARRIER()                                                          \
    do {                                                                          \
      asm volatile("s_waitcnt vmcnt(0)" ::: "memory");                            \
      __syncthreads();                                                            \
      if (tid == 0) {                                                             \
        int prev = __hip_atomic_fetch_add(leaf, 1, __ATOMIC_RELAXED,              \
                                          __HIP_MEMORY_SCOPE_AGENT);              \
        bool released = false;                                                    \
        if (prev == 16 * epoch - 1) {                                             \
          int rprev = __hip_atomic_fetch_add(rootc, 1, __ATOMIC_RELAXED,          \
                                             __HIP_MEMORY_SCOPE_AGENT);          \
          if (rprev == 16 * epoch - 1) {                                          \
            _Pragma("unroll")                                                     \
            for (int i = 0; i < 16; ++i)                                          \
              st32c(bar + 64 * (17 + i), epoch);                                  \
            released = true;                                                      \
          }                                                                       \
        }                                                                         \
        if (!released) {                                                          \
          while (__hip_atomic_load(relme, __ATOMIC_RELAXED,                       \
                                   __HIP_MEMORY_SCOPE_AGENT) < epoch)             \
            __builtin_amdgcn_s_sleep(2);                                          \
        }                                                                         \
        if (is_leader) {                                                          \
          asm volatile("buffer_inv sc1" ::: "memory");                            \
          asm volatile("s_waitcnt vmcnt(0)" ::: "memory");                        \
          st32c(invflag, epoch);                                                  \
        } else {                                                                  \
          while (ld32c(invflag) < epoch)                                          \
            __builtin_amdgcn_s_sleep(1);                                          \
        }                                                                         \
      }                                                                           \
      epoch++;                                                                    \
      __syncthreads();                                                            \
    } while (0)

  GRID_BARRIER();

  const f16x8* Av = (const f16x8*)Alds;

  for (int t = 0; t < T; ++t) {
    const int wp = t & 1, rp = wp ^ 1;
    #pragma unroll 1
    for (int l = 0; l < 2; ++l) {
      // ---- B source for this wave's K-quarter ----
      const f16* src; int col0;
      const int kbase = wave * 512;
      if (l == 0) {
        if (kbase < 1024) { src = (t == 0) ? xf16 : hbuf + (size_t)(2 + rp) * NBAT * HID; col0 = kbase; }
        else              { src = hbuf + (size_t)(0 + rp) * NBAT * HID; col0 = kbase - 1024; }
      } else {
        if (kbase < 1024) { src = hbuf + (size_t)(0 + wp) * NBAT * HID; col0 = kbase; }
        else              { src = hbuf + (size_t)(2 + rp) * NBAT * HID; col0 = kbase - 1024; }
      }
      const f16* r0 = src + (size_t)(l15 +  0) * HID + col0 + quad * 8;
      const f16* r1 = src + (size_t)(l15 + 16) * HID + col0 + quad * 8;
      const f16* r2 = src + (size_t)(l15 + 32) * HID + col0 + quad * 8;
      const f16* r3 = src + (size_t)(l15 + 48) * HID + col0 + quad * 8;

      // ---- MFMA: 16 gate-rows x 64 batch over this wave's K=512 ----
      int aoff = (l * 16 + l15) * AVEC + wave * 64 + quad;
      f32x4 a0 = {0.f, 0.f, 0.f, 0.f}, a1 = a0, a2 = a0, a3 = a0;
      #pragma unroll
      for (int kk = 0; kk < 16; ++kk) {
        f16x8 af  = Av[aoff + kk * 4];
        f16x8 b0v = *(const f16x8*)(r0 + kk * 32);
        f16x8 b1v = *(const f16x8*)(r1 + kk * 32);
        f16x8 b2v = *(const f16x8*)(r2 + kk * 32);
        f16x8 b3v = *(const f16x8*)(r3 + kk * 32);
        a0 = __builtin_amdgcn_mfma_f32_16x16x32_f16(af, b0v, a0, 0, 0, 0);
        a1 = __builtin_amdgcn_mfma_f32_16x16x32_f16(af, b1v, a1, 0, 0, 0);
        a2 = __builtin_amdgcn_mfma_f32_16x16x32_f16(af, b2v, a2, 0, 0, 0);
        a3 = __builtin_amdgcn_mfma_f32_16x16x32_f16(af, b3v, a3, 0, 0, 0);
      }
      // ---- partials to LDS scratch (C/D: col=lane&15, row=quad*4+reg) ----
      float* sc = scr + wave * 1024;
      #pragma unroll
      for (int r = 0; r < 4; ++r) {
        int base = (quad * 4 + r) * 64 + l15;
        sc[base +  0] = a0[r];
        sc[base + 16] = a1[r];
        sc[base + 32] = a2[r];
        sc[base + 48] = a3[r];
      }
      __syncthreads();

      // ---- elementwise: thread = (unit j, batch n); all gates CU-local ----
      {
        int j = tid >> 6, n = tid & 63;
        float gate[4];
        #pragma unroll
        for (int g = 0; g < 4; ++g) {
          int b0i = (g * 4 + j) * 64 + n;
          gate[g] = scr[b0i] + scr[1024 + b0i] + scr[2048 + b0i] + scr[3072 + b0i]
                  + biasS[l * 16 + g * 4 + j];
        }
        float cold = cS[l * 256 + j * 64 + n];
        float cn = sigm(gate[1]) * cold + sigm(gate[0]) * tanh_f(gate[2]);
        float hn = sigm(gate[3]) * tanh_f(cn);
        cS[l * 256 + j * 64 + n] = cn;
        hS[n * 4 + j] = (f16)hn;          // LDS transpose for coalesced store
      }
      __syncthreads();

      // ---- pack + coherent store: 8B h-store (+16B out on l==1), wave 0 only ----
      if (tid < 64) {
        int n = tid;
        union { u64 q; f16 h[4]; } pk;
        pk.q = *(const u64*)(hS + n * 4);
        st64c(hbuf + (size_t)(l * 2 + wp) * NBAT * HID + (size_t)n * HID + blk * 4, pk.q);
        if (l == 1) {
          union { u64 q; float f[2]; } o0, o1;
          o0.f[0] = (float)pk.h[0]; o0.f[1] = (float)pk.h[1];
          o1.f[0] = (float)pk.h[2]; o1.f[1] = (float)pk.h[3];
          float* op = out + (size_t)n * T * HID + (size_t)t * HID + blk * 4;
          st64c(op, o0.q);
          st64c(op + 2, o1.q);
        }
      }
      GRID_BARRIER();
    }
  }
}

extern "C" void kernel_launch(void* const* d_in, const int* in_sizes, int n_in,
                              void* d_out, int out_size, void* d_ws, size_t ws_size,
                              hipStream_t stream) {
  const float* x0  = (const float*)d_in[0];
  const float* h0  = (const float*)d_in[1];
  const float* c0  = (const float*)d_in[2];
  const float* Wih = (const float*)d_in[3];
  const float* Whh = (const float*)d_in[4];
  const float* bih = (const float*)d_in[5];
  const float* bhh = (const float*)d_in[6];
  const int* lenp  = (const int*)d_in[7];
  float* out = (float*)d_out;

  int* bar  = (int*)d_ws;
  f16* hbuf = (f16*)((char*)d_ws + 16384);        // 4 x 64 x 1024 f16 = 512 KB
  f16* xbuf = hbuf + (size_t)4 * NBAT * HID;      // 64 x 1024 f16 = 128 KB

  hipFuncSetAttribute((const void*)lstm_kernel,
                      hipFuncAttributeMaxDynamicSharedMemorySize, LDS_BYTES);

  bar_init<<<1, 1024, 0, stream>>>(bar);

  void* args[] = {&x0, &h0, &c0, &Wih, &Whh, &bih, &bhh, &lenp, &out, &bar, &hbuf, &xbuf};
  hipLaunchCooperativeKernel((void*)lstm_kernel, dim3(NBLK), dim3(NTHR),
                             args, LDS_BYTES, stream);
}

// Round 7
// 2119.548 us; speedup vs baseline: 8.8022x; 1.3928x over previous
//
#include <hip/hip_runtime.h>
#include <hip/hip_fp16.h>

#define HID   1024
#define NBAT  64
#define NBLK  256
#define NTHR  256
#define AROW  2056              // 2048 + 8 pad (f16 elems)
#define AVEC  257               // AROW/8
#define PLANE 65536             // f16 elems per activation plane: [256 blk][64 n][4 j]

typedef _Float16 f16;
typedef unsigned long long u64;
typedef __attribute__((ext_vector_type(8))) _Float16 f16x8;
typedef __attribute__((ext_vector_type(4))) float f32x4;

// LDS layout (bytes)
#define A_BYTES   (2 * 16 * AROW * 2)    // 131584
#define SCR_OFF   A_BYTES                // f32 [4 kg][16 rows][64 batch] = 16384
#define C_OFF     (SCR_OFF + 16384)      // f32 [2][4][64] = 2048
#define BIAS_OFF  (C_OFF + 2048)         // f32 [2][16] = 128
#define HS_OFF    (BIAS_OFF + 128)       // f16 [64][4] = 512
#define LDS_BYTES (HS_OFF + 512)         // 150656 < 160 KiB

// barrier ints (256B-spaced): leaf i: bar[64*i] i<16 | root: bar[64*16] |
// release flag i: bar[64*(17+i)] i<16 | xcd elect x: bar[64*(33+x)] x<8
#define BAR_INTS  (64 * 41)

__device__ __forceinline__ float sigm(float x) { return 1.f / (1.f + __expf(-x)); }
__device__ __forceinline__ float tanh_f(float x) {
  float xc = fminf(fmaxf(x, -10.f), 10.f);
  float e = __expf(2.f * xc);
  return (e - 1.f) / (e + 1.f);
}

// sc1 write-through store (coherent via MALL)
__device__ __forceinline__ void st64c(void* p, u64 v) {
  __hip_atomic_store((u64*)p, v, __ATOMIC_RELAXED, __HIP_MEMORY_SCOPE_AGENT);
}

__global__ void bar_init(int* bar) {
  int i = threadIdx.x;
  #pragma unroll
  for (int k = 0; k < 3; ++k) {
    int idx = i + k * 1024;
    if (idx < BAR_INTS) bar[idx] = 0;
  }
}

// Block b owns hidden units [4b,4b+4) for both layers. Weights f16 in LDS.
// Activation planes in ws, BLOCK-CONTIGUOUS: plane[srcblk][n][j] f16 so each
// block's per-phase h store is one 512B contiguous chunk (full-line
// write-through; fixes the 8x WRITE_SIZE amplification seen in R6).
// Planes: l0h[2] (step parity), l1h[2], x (t=0 only).
// Barrier: tree arrival (16 leaves + root), release via far-atomic fetch_add
// on 16 flags, polls via fetch_add(0) (memory-side, always fresh, no
// write-through). Leader-per-XCD buffer_inv moved into mid-phase (after its
// B reads; the next phase's stale-risk plane is untouched by current-phase
// fills on that XCD; barrier vmcnt(0) drain covers inv completion).
__global__ __launch_bounds__(NTHR, 1) void lstm_kernel(
    const float* __restrict__ x0, const float* __restrict__ h0,
    const float* __restrict__ c0, const float* __restrict__ Wih,
    const float* __restrict__ Whh, const float* __restrict__ bih,
    const float* __restrict__ bhh, const int* __restrict__ lenp,
    float* __restrict__ out, int* __restrict__ bar, f16* __restrict__ planes)
{
  extern __shared__ char smem[];
  f16*   Alds  = (f16*)smem;
  float* scr   = (float*)(smem + SCR_OFF);
  float* cS    = (float*)(smem + C_OFF);
  float* biasS = (float*)(smem + BIAS_OFF);
  f16*   hS    = (f16*)(smem + HS_OFF);     // [n][j] transpose buffer

  const int tid  = threadIdx.x;
  const int blk  = blockIdx.x;
  const int wave = tid >> 6;
  const int lane = tid & 63;
  const int quad = lane >> 4;
  const int l15  = lane & 15;
  const int T    = *lenp;

  f16* l0P[2] = { planes,             planes + PLANE };
  f16* l1P[2] = { planes + 2 * PLANE, planes + 3 * PLANE };
  f16* xP     =   planes + 4 * PLANE;

  const int leafid = blk & 15;
  int* leaf  = bar + 64 * leafid;
  int* rootc = bar + 64 * 16;
  int* relme = bar + 64 * (17 + leafid);

  // ---- physical XCD id + one-time leader election ----
  unsigned xcc;
  asm volatile("s_getreg_b32 %0, hwreg(HW_REG_XCC_ID)" : "=s"(xcc));
  xcc &= 7;
  int is_leader = 0;
  if (tid == 0) {
    int p = __hip_atomic_fetch_add(bar + 64 * (33 + xcc), 1, __ATOMIC_RELAXED,
                                   __HIP_MEMORY_SCOPE_AGENT);
    is_leader = (p == 0);
  }

  // ---- stage weights (f32 -> f16) into LDS ----
  {
    int r    = tid >> 2;
    int part = tid & 3;
    int l    = r >> 5;
    int m    = (r >> 1) & 15;
    int half = r & 1;
    int g    = m >> 2, j = m & 3;
    size_t grow = (size_t)g * HID + blk * 4 + j;
    const float* srcW = (half ? Whh : Wih) + ((size_t)l * 4 * HID + grow) * HID + part * 256;
    f16x8* dst = (f16x8*)(Alds + (size_t)(l * 16 + m) * AROW + half * HID + part * 256);
    const float4* s4 = (const float4*)srcW;
    #pragma unroll 4
    for (int i = 0; i < 32; ++i) {
      float4 w0 = s4[2 * i], w1 = s4[2 * i + 1];
      f16x8 o = {(f16)w0.x, (f16)w0.y, (f16)w0.z, (f16)w0.w,
                 (f16)w1.x, (f16)w1.y, (f16)w1.z, (f16)w1.w};
      dst[i] = o;
    }
  }
  // ---- biases ----
  if (tid < 32) {
    int l = tid >> 4, m = tid & 15;
    int g = m >> 2, j = m & 3;
    size_t row = (size_t)g * HID + blk * 4 + j;
    biasS[l * 16 + m] = bih[(size_t)l * 4 * HID + row] + bhh[(size_t)l * 4 * HID + row];
  }
  // ---- c state (LDS, CU-local) ----
  {
    int j = tid >> 6, n = tid & 63;
    #pragma unroll
    for (int l = 0; l < 2; ++l)
      cS[l * 256 + j * 64 + n] =
          c0[(size_t)l * NBAT * HID + (size_t)n * HID + blk * 4 + j];
  }
  // ---- h0 -> parity-1 planes (block-contiguous, 8B/lane) ----
  if (tid < 128) {
    int l = tid >> 6, n = tid & 63;
    const float* hp = h0 + (size_t)l * NBAT * HID + (size_t)n * HID + blk * 4;
    union { u64 q; f16 h[4]; } pk;
    pk.h[0] = (f16)hp[0]; pk.h[1] = (f16)hp[1]; pk.h[2] = (f16)hp[2]; pk.h[3] = (f16)hp[3];
    st64c((l == 0 ? l0P[1] : l1P[1]) + blk * 256 + n * 4, pk.q);
  }
  // ---- x0 -> xP (each block stages its own 4-unit slot) ----
  if (tid < 64) {
    int n = tid;
    const float* xp = x0 + (size_t)n * HID + blk * 4;
    union { u64 q; f16 h[4]; } pk;
    pk.h[0] = (f16)xp[0]; pk.h[1] = (f16)xp[1]; pk.h[2] = (f16)xp[2]; pk.h[3] = (f16)xp[3];
    st64c(xP + blk * 256 + n * 4, pk.q);
  }
  // one-time safety inv (poison/stale lines) before first arrival
  if (wave == 0) asm volatile("buffer_inv sc1" ::: "memory");

  // ---- grid barrier: tree arrival, far-atomic release + polls, no inv ----
  int epoch = 1;
  #define GRID_BARRIER()                                                          \
    do {                                                                          \
      asm volatile("s_waitcnt vmcnt(0)" ::: "memory");                            \
      __syncthreads();                                                            \
      if (tid == 0) {                                                             \
        int prev = __hip_atomic_fetch_add(leaf, 1, __ATOMIC_RELAXED,              \
                                          __HIP_MEMORY_SCOPE_AGENT);              \
        bool released = false;                                                    \
        if (prev == 16 * epoch - 1) {                                             \
          int rprev = __hip_atomic_fetch_add(rootc, 1, __ATOMIC_RELAXED,          \
                                             __HIP_MEMORY_SCOPE_AGENT);          \
          if (rprev == 16 * epoch - 1) {                                          \
            _Pragma("unroll")                                                     \
            for (int i = 0; i < 16; ++i)                                          \
              __hip_atomic_fetch_add(bar + 64 * (17 + i), 1, __ATOMIC_RELAXED,    \
                                     __HIP_MEMORY_SCOPE_AGENT);                   \
            released = true;                                                      \
          }                                                                       \
        }                                                                         \
        if (!released) {                                                          \
          while (__hip_atomic_fetch_add(relme, 0, __ATOMIC_RELAXED,               \
                                        __HIP_MEMORY_SCOPE_AGENT) < epoch)        \
            __builtin_amdgcn_s_sleep(1);                                          \
        }                                                                         \
      }                                                                           \
      epoch++;                                                                    \
      __syncthreads();                                                            \
    } while (0)

  GRID_BARRIER();

  const f16x8* Av = (const f16x8*)Alds;

  for (int t = 0; t < T; ++t) {
    const int wp = t & 1, rp = wp ^ 1;
    #pragma unroll 1
    for (int l = 0; l < 2; ++l) {
      // ---- B source: first-half plane (k<1024) / second-half plane ----
      const f16 *pA, *pB;
      if (l == 0) { pA = (t == 0) ? xP : l1P[rp]; pB = l0P[rp]; }
      else        { pA = l0P[wp];                 pB = l1P[rp]; }
      const f16* psrc = (wave >= 2) ? pB : pA;
      const int ubq = (wave & 1) * 128 + quad * 2;   // unit-block base (+kk*8)
      const f16* pr0 = psrc + ubq * 256 + (l15 +  0) * 4;
      const f16* pr1 = psrc + ubq * 256 + (l15 + 16) * 4;
      const f16* pr2 = psrc + ubq * 256 + (l15 + 32) * 4;
      const f16* pr3 = psrc + ubq * 256 + (l15 + 48) * 4;

      // ---- MFMA: 16 gate-rows x 64 batch over this wave's K=512 ----
      int aoff = (l * 16 + l15) * AVEC + wave * 64 + quad;
      f32x4 a0 = {0.f, 0.f, 0.f, 0.f}, a1 = a0, a2 = a0, a3 = a0;
      #pragma unroll
      for (int kk = 0; kk < 16; ++kk) {
        f16x8 af = Av[aoff + kk * 4];
        union { u64 q[2]; f16x8 v; } b0, b1, b2, b3;
        const f16* k0 = pr0 + kk * 2048;
        const f16* k1 = pr1 + kk * 2048;
        const f16* k2 = pr2 + kk * 2048;
        const f16* k3 = pr3 + kk * 2048;
        b0.q[0] = *(const u64*)k0; b0.q[1] = *(const u64*)(k0 + 256);
        b1.q[0] = *(const u64*)k1; b1.q[1] = *(const u64*)(k1 + 256);
        b2.q[0] = *(const u64*)k2; b2.q[1] = *(const u64*)(k2 + 256);
        b3.q[0] = *(const u64*)k3; b3.q[1] = *(const u64*)(k3 + 256);
        a0 = __builtin_amdgcn_mfma_f32_16x16x32_f16(af, b0.v, a0, 0, 0, 0);
        a1 = __builtin_amdgcn_mfma_f32_16x16x32_f16(af, b1.v, a1, 0, 0, 0);
        a2 = __builtin_amdgcn_mfma_f32_16x16x32_f16(af, b2.v, a2, 0, 0, 0);
        a3 = __builtin_amdgcn_mfma_f32_16x16x32_f16(af, b3.v, a3, 0, 0, 0);
      }
      // ---- partials to LDS scratch (C/D: col=lane&15, row=quad*4+reg) ----
      float* sc = scr + wave * 1024;
      #pragma unroll
      for (int r = 0; r < 4; ++r) {
        int base = (quad * 4 + r) * 64 + l15;
        sc[base +  0] = a0[r];
        sc[base + 16] = a1[r];
        sc[base + 32] = a2[r];
        sc[base + 48] = a3[r];
      }
      __syncthreads();

      // ---- leader inv for the NEXT phase's coherence (off critical path) ----
      if (is_leader) asm volatile("buffer_inv sc1" ::: "memory");

      // ---- elementwise: thread = (unit j, batch n) ----
      {
        int j = tid >> 6, n = tid & 63;
        float gate[4];
        #pragma unroll
        for (int g = 0; g < 4; ++g) {
          int b0i = (g * 4 + j) * 64 + n;
          gate[g] = scr[b0i] + scr[1024 + b0i] + scr[2048 + b0i] + scr[3072 + b0i]
                  + biasS[l * 16 + g * 4 + j];
        }
        float cold = cS[l * 256 + j * 64 + n];
        float cn = sigm(gate[1]) * cold + sigm(gate[0]) * tanh_f(gate[2]);
        float hn = sigm(gate[3]) * tanh_f(cn);
        cS[l * 256 + j * 64 + n] = cn;
        hS[n * 4 + j] = (f16)hn;
      }
      __syncthreads();

      // ---- h store: ONE contiguous 512B chunk per block (+ out on l==1) ----
      if (tid < 64) {
        int n = tid;
        union { u64 q; f16 h[4]; } pk;
        pk.q = *(const u64*)(hS + n * 4);
        st64c((l == 0 ? l0P[wp] : l1P[wp]) + blk * 256 + n * 4, pk.q);
        if (l == 1) {
          union { u64 q; float f[2]; } o0, o1;
          o0.f[0] = (float)pk.h[0]; o0.f[1] = (float)pk.h[1];
          o1.f[0] = (float)pk.h[2]; o1.f[1] = (float)pk.h[3];
          float* op = out + (size_t)n * T * HID + (size_t)t * HID + blk * 4;
          st64c(op, o0.q);
          st64c(op + 2, o1.q);
        }
      }
      GRID_BARRIER();
    }
  }
}

extern "C" void kernel_launch(void* const* d_in, const int* in_sizes, int n_in,
                              void* d_out, int out_size, void* d_ws, size_t ws_size,
                              hipStream_t stream) {
  const float* x0  = (const float*)d_in[0];
  const float* h0  = (const float*)d_in[1];
  const float* c0  = (const float*)d_in[2];
  const float* Wih = (const float*)d_in[3];
  const float* Whh = (const float*)d_in[4];
  const float* bih = (const float*)d_in[5];
  const float* bhh = (const float*)d_in[6];
  const int* lenp  = (const int*)d_in[7];
  float* out = (float*)d_out;

  int* bar    = (int*)d_ws;
  f16* planes = (f16*)((char*)d_ws + 16384);   // 5 planes x 128 KB

  hipFuncSetAttribute((const void*)lstm_kernel,
                      hipFuncAttributeMaxDynamicSharedMemorySize, LDS_BYTES);

  bar_init<<<1, 1024, 0, stream>>>(bar);

  void* args[] = {&x0, &h0, &c0, &Wih, &Whh, &bih, &bhh, &lenp, &out, &bar, &planes};
  hipLaunchCooperativeKernel((void*)lstm_kernel, dim3(NBLK), dim3(NTHR),
                             args, LDS_BYTES, stream);
}